// Round 3
// baseline (114.097 us; speedup 1.0000x reference)
//
#include <hip/hip_runtime.h>

#define NI 12   // input props
#define NR 6    // rules
#define NJ 2    // templates per rule
#define NL 2    // feature width
#define NV 4    // variables

typedef float v2f __attribute__((ext_vector_type(2)));

// exp2(n) on n in [-2, 0], degree-4 Chebyshev-derived poly, abs err ~1e-4.
#define EC0 0.9999561f
#define EC1 0.6919824f
#define EC2 0.2353942f
#define EC3 0.0482908f
#define EC4 0.0049248f

__global__ __launch_bounds__(256) void
abstraction_fused(const float4* __restrict__ feat4,
                  const float* __restrict__ templates,
                  const float* __restrict__ gammas,
                  const float* __restrict__ body_W,
                  const float* __restrict__ body_b,
                  const float* __restrict__ head_W,
                  const float* __restrict__ head_b,
                  float4* __restrict__ out4, int B) {
    // Staging buffer: 256 elements x 6 float4 (24576 B). Reused for output
    // staging (768 float4) after the features are consumed.
    __shared__ float4 sF[256 * 6];
    __shared__ float sG[NR * NJ * 5];
    __shared__ float sM[NR * NL * NJ * NL];
    __shared__ float sC[NR * NL];

    const int t = threadIdx.x;
    const float LOG2E = 1.4426950408889634f;

    // ---- derived parameters into LDS (redundant per block, tiny) ----
    if (t < NR * NJ) {
        const int g = t;
        float g0 = fminf(fmaxf(gammas[g * NL + 0], 0.f), 1.f);
        float g1 = fminf(fmaxf(gammas[g * NL + 1], 0.f), 1.f);
        float w0 = 1.f - g0, w1 = 1.f - g1;
        float t0 = templates[g * NL + 0], t1 = templates[g * NL + 1];
        float wt0 = w0 * t0, wt1 = w1 * t1;
        float c0 = wt0 * t0 + wt1 * t1;
        sG[g * 5 + 0] = 2.f * LOG2E * wt0;
        sG[g * 5 + 1] = 2.f * LOG2E * wt1;
        sG[g * 5 + 2] = -LOG2E * w0;
        sG[g * 5 + 3] = -LOG2E * w1;
        sG[g * 5 + 4] = -LOG2E * c0;
    } else if (t >= 64 && t < 64 + NR * NL) {
        const int idx = t - 64;
        const int r = idx >> 1, l = idx & 1;
        float acc = head_b[r * NL + l];
        #pragma unroll
        for (int v = 0; v < NV; ++v) {
            float bs = body_b[(r * NJ + 0) * NV + v] + body_b[(r * NJ + 1) * NV + v];
            acc = fmaf(head_W[(r * NL + l) * NV + v], bs, acc);
        }
        sC[idx] = acc;
    } else if (t >= 128 && t < 128 + NR * NL * NJ * NL) {
        const int idx = t - 128;
        const int lp = idx & 1, j = (idx >> 1) & 1, l = (idx >> 2) & 1, r = idx >> 3;
        float acc = 0.f;
        #pragma unroll
        for (int v = 0; v < NV; ++v)
            acc = fmaf(head_W[(r * NL + l) * NV + v],
                       body_W[((r * NJ + j) * NV + v) * NL + lp], acc);
        sM[idx] = acc;
    }

    // ---- stage-in: 6 fully-coalesced float4 loads per thread ----
    // LDS slot for (element e, chunk c) is 6e + (c+e)%6  (mod-6 swizzle so the
    // per-element readback is ~conflict-free).
    const int tileBase4 = blockIdx.x * (256 * 6);
    const int maxIdx4 = B * 6 - 1;
    #pragma unroll
    for (int k = 0; k < 6; ++k) {
        int m = t + 256 * k;
        int gi = tileBase4 + m; if (gi > maxIdx4) gi = maxIdx4;
        float4 v = feat4[gi];
        int e = (m * 683) >> 12;          // m/6 for m<4096
        int s = m + e;                    // (c+e) mod 6 == (m+e) mod 6
        int q6 = (s * 683) >> 12;
        sF[6 * e + (s - 6 * q6)] = v;
    }
    __syncthreads();

    // ---- read own 24 features from LDS (swizzle-aware, static reg targets) ----
    int r6 = t - 6 * ((t * 683) >> 12);   // t % 6
    float f0[NI], f1[NI];
    #pragma unroll
    for (int c = 0; c < 6; ++c) {
        int cc = c + r6; if (cc >= 6) cc -= 6;
        float4 v = sF[6 * t + cc];
        f0[2 * c + 0] = v.x; f1[2 * c + 0] = v.y;
        f0[2 * c + 1] = v.z; f1[2 * c + 1] = v.w;
    }
    __syncthreads();   // feature area of sF now free for output staging

    // ---- compute ----
    const v2f C0v = EC0, C1v = EC1, C2v = EC2, C3v = EC3, C4v = EC4;
    float o[NR * NL];
    #pragma unroll
    for (int r = 0; r < NR; ++r) {
        float o0 = sC[r * 2 + 0];
        float o1 = sC[r * 2 + 1];
        #pragma unroll
        for (int j = 0; j < NJ; ++j) {
            const int g = r * NJ + j;
            const v2f A0 = sG[g * 5 + 0];
            const v2f A1 = sG[g * 5 + 1];
            const v2f W0 = sG[g * 5 + 2];
            const v2f W1 = sG[g * 5 + 3];
            const v2f Cn = sG[g * 5 + 4];
            v2f den = 0.f, a0 = 0.f, a1 = 0.f;
            #pragma unroll
            for (int i = 0; i < NI; i += 2) {
                v2f X0 = { f0[i], f0[i + 1] };
                v2f X1 = { f1[i], f1[i + 1] };
                // n = X0*(W0*X0+A0) + X1*(W1*X1+A1) + Cn   in [-1.8, 0]
                v2f n = __builtin_elementwise_fma(
                            X0, __builtin_elementwise_fma(W0, X0, A0),
                            __builtin_elementwise_fma(
                                X1, __builtin_elementwise_fma(W1, X1, A1), Cn));
                // p = exp2(n) via degree-4 poly (all v_pk_fma_f32)
                v2f p = __builtin_elementwise_fma(
                            n, __builtin_elementwise_fma(
                                n, __builtin_elementwise_fma(
                                    n, __builtin_elementwise_fma(n, C4v, C3v),
                                    C2v), C1v), C0v);
                den += p;
                a0 = __builtin_elementwise_fma(p, X0, a0);
                a1 = __builtin_elementwise_fma(p, X1, a1);
            }
            float d = den.x + den.y;
            float rinv = __builtin_amdgcn_rcpf(d);
            float s0 = (a0.x + a0.y) * rinv;
            float s1 = (a1.x + a1.y) * rinv;
            const float m00 = sM[((r * 2 + 0) * 2 + j) * 2 + 0];
            const float m01 = sM[((r * 2 + 0) * 2 + j) * 2 + 1];
            const float m10 = sM[((r * 2 + 1) * 2 + j) * 2 + 0];
            const float m11 = sM[((r * 2 + 1) * 2 + j) * 2 + 1];
            o0 = fmaf(s0, m00, o0); o0 = fmaf(s1, m01, o0);
            o1 = fmaf(s0, m10, o1); o1 = fmaf(s1, m11, o1);
        }
        o[r * 2 + 0] = o0;
        o[r * 2 + 1] = o1;
    }

    // ---- stage-out through LDS, then 3 coalesced float4 stores ----
    // slot for (element e, chunk c): 3e + (c+e)%3
    int r3 = t - 3 * ((t * 1366) >> 12);  // t % 3
    #pragma unroll
    for (int c = 0; c < 3; ++c) {
        int cc = c + r3; if (cc >= 3) cc -= 3;
        sF[3 * t + cc] = make_float4(o[4 * c + 0], o[4 * c + 1],
                                     o[4 * c + 2], o[4 * c + 3]);
    }
    __syncthreads();
    const int outBase4 = blockIdx.x * (256 * 3);
    const int maxOut4 = B * 3;
    #pragma unroll
    for (int k = 0; k < 3; ++k) {
        int m = t + 256 * k;
        int e = (m * 1366) >> 12;         // m/3 for m<4096
        int s = m - 2 * e;                // c + e  (c = m - 3e)
        int q3 = (s * 1366) >> 12;
        float4 v = sF[3 * e + (s - 3 * q3)];
        if (outBase4 + m < maxOut4) out4[outBase4 + m] = v;
    }
}

extern "C" void kernel_launch(void* const* d_in, const int* in_sizes, int n_in,
                              void* d_out, int out_size, void* d_ws, size_t ws_size,
                              hipStream_t stream) {
    (void)n_in; (void)out_size; (void)d_ws; (void)ws_size;
    const float4* feat4    = (const float4*)d_in[0];
    const float* templates = (const float*)d_in[1];
    const float* gammas    = (const float*)d_in[2];
    const float* body_W    = (const float*)d_in[3];
    const float* body_b    = (const float*)d_in[4];
    const float* head_W    = (const float*)d_in[5];
    const float* head_b    = (const float*)d_in[6];
    float4* out4 = (float4*)d_out;

    int B = in_sizes[0] / (NI * NL);
    int blocks = (B + 255) / 256;
    hipLaunchKernelGGL(abstraction_fused, dim3(blocks), dim3(256), 0, stream,
                       feat4, templates, gammas, body_W, body_b, head_W, head_b,
                       out4, B);
}